// Round 16
// baseline (162.885 us; speedup 1.0000x reference)
//
#include <hip/hip_runtime.h>

#define N 1024
#define DIM 2048

typedef unsigned long long u64;

__device__ __forceinline__ u64 umin64(u64 a, u64 b){ return a < b ? a : b; }

// map linear id in [0,136) to lower-triangle block coords (by >= bx), 16x16 blocks
__device__ __forceinline__ void tri_map(int lid, int* by, int* bx){
  int y = (int)((sqrtf(8.0f * lid + 1.0f) - 1.0f) * 0.5f);
  while ((y + 1) * (y + 2) / 2 <= lid) y++;
  while (y * (y + 1) / 2 > lid) y--;
  *by = y;
  *bx = lid - y * (y + 1) / 2;
}

// ---------------- row norms ----------------
__global__ __launch_bounds__(256) void rownorm_kernel(const float* __restrict__ x, float* __restrict__ xx){
  int i = blockIdx.x, t = threadIdx.x;
  const float4* row = (const float4*)(x + (size_t)i * DIM);
  float s = 0.f;
  #pragma unroll
  for (int q = 0; q < 2; q++){
    float4 v = row[t + q*256];
    s += v.x*v.x + v.y*v.y + v.z*v.z + v.w*v.w;
  }
  #pragma unroll
  for (int off = 32; off > 0; off >>= 1) s += __shfl_down(s, off);
  __shared__ float sm[4];
  if ((t & 63) == 0) sm[t >> 6] = s;
  __syncthreads();
  if (t == 0) xx[i] = sm[0] + sm[1] + sm[2] + sm[3];
}

// ---------------- x@x^T partials: tri grid, split-K, single-LDS + register prefetch ----------------
// r11-proven structure: plain __launch_bounds__(256), 4x4 tile.
__global__ __launch_bounds__(256) void gemm_split_kernel(const float* __restrict__ x,
    float* __restrict__ p0, float* __restrict__ p1, int kc){
  __shared__ __align__(16) float As[32][64];
  __shared__ __align__(16) float Bs[32][64];
  int by, bx; tri_map(blockIdx.x, &by, &bx);
  int z = blockIdx.y;
  int t = threadIdx.x;
  int tx = t & 15, ty = t >> 4;
  int i0 = by * 64, j0 = bx * 64;
  int kbase = z * kc;
  int nslab = kc >> 5;
  int row0 = t >> 3, kq = t & 7;
  int sw = kq << 3;

  float4 fa0 = *(const float4*)&x[(size_t)(i0+row0)*DIM    + kbase + kq*4];
  float4 fa1 = *(const float4*)&x[(size_t)(i0+row0+32)*DIM + kbase + kq*4];
  float4 fb0 = *(const float4*)&x[(size_t)(j0+row0)*DIM    + kbase + kq*4];
  float4 fb1 = *(const float4*)&x[(size_t)(j0+row0+32)*DIM + kbase + kq*4];

  float acc[4][4] = {};
  for (int s = 0; s < nslab; s++){
    {
      float va0[4] = {fa0.x, fa0.y, fa0.z, fa0.w};
      float va1[4] = {fa1.x, fa1.y, fa1.z, fa1.w};
      float vb0[4] = {fb0.x, fb0.y, fb0.z, fb0.w};
      float vb1[4] = {fb1.x, fb1.y, fb1.z, fb1.w};
      #pragma unroll
      for (int e2 = 0; e2 < 4; e2++){
        As[kq*4+e2][row0 ^ sw]      = va0[e2];
        As[kq*4+e2][(row0+32) ^ sw] = va1[e2];
        Bs[kq*4+e2][row0 ^ sw]      = vb0[e2];
        Bs[kq*4+e2][(row0+32) ^ sw] = vb1[e2];
      }
    }
    __syncthreads();
    if (s + 1 < nslab){
      int k0 = kbase + (s+1)*32;
      fa0 = *(const float4*)&x[(size_t)(i0+row0)*DIM    + k0 + kq*4];
      fa1 = *(const float4*)&x[(size_t)(i0+row0+32)*DIM + k0 + kq*4];
      fb0 = *(const float4*)&x[(size_t)(j0+row0)*DIM    + k0 + kq*4];
      fb1 = *(const float4*)&x[(size_t)(j0+row0+32)*DIM + k0 + kq*4];
    }
    #pragma unroll
    for (int kk = 0; kk < 32; kk++){
      int swk = (kk >> 2) << 3;
      float4 a4 = *(const float4*)&As[kk][(ty*4) ^ swk];
      float4 b4 = *(const float4*)&Bs[kk][(tx*4) ^ swk];
      float av[4] = {a4.x, a4.y, a4.z, a4.w};
      float bv[4] = {b4.x, b4.y, b4.z, b4.w};
      #pragma unroll
      for (int r = 0; r < 4; r++){
        #pragma unroll
        for (int c = 0; c < 4; c++) acc[r][c] = fmaf(av[r], bv[c], acc[r][c]);
      }
    }
    __syncthreads();
  }
  float* P = (z == 0) ? p0 : p1 + (size_t)(z - 1) * N * N;
  #pragma unroll
  for (int r = 0; r < 4; r++){
    #pragma unroll
    for (int c = 0; c < 4; c++){
      int i = i0 + ty*4 + r, j = j0 + tx*4 + c;
      P[(size_t)i * N + j] = acc[r][c];
    }
  }
}

// ---------------- combine -> D0 = clamp(xx_i+xx_j-2*dot,0), mirror; 2 row-halves/tile ----------------
__global__ __launch_bounds__(256) void gemm_combine_kernel(
    const float* __restrict__ p0, const float* __restrict__ p1,
    int nsplit, const float* __restrict__ xx, float* __restrict__ D){
  __shared__ float Ts[32][68];
  int by, bx; tri_map(blockIdx.x, &by, &bx);
  int h = blockIdx.y;
  int t = threadIdx.x;
  int tc = t & 15, tr = t >> 4;
  int i0 = by * 64 + h * 32, j0 = bx * 64;
  float4 xj = *(const float4*)&xx[j0 + tc*4];
  #pragma unroll
  for (int rr = 0; rr < 2; rr++){
    int r = tr*2 + rr;
    int i = i0 + r;
    size_t off = (size_t)i * N + j0 + tc*4;
    float4 s = *(const float4*)&p0[off];
    for (int z = 1; z < nsplit; z++){
      float4 q = *(const float4*)&p1[(size_t)(z-1)*N*N + off];
      s.x += q.x; s.y += q.y; s.z += q.z; s.w += q.w;
    }
    float xxi = xx[i];
    float4 o;
    o.x = xxi + xj.x - 2.0f*s.x; o.x = (o.x > 0.f) ? o.x : 0.f;
    o.y = xxi + xj.y - 2.0f*s.y; o.y = (o.y > 0.f) ? o.y : 0.f;
    o.z = xxi + xj.z - 2.0f*s.z; o.z = (o.z > 0.f) ? o.z : 0.f;
    o.w = xxi + xj.w - 2.0f*s.w; o.w = (o.w > 0.f) ? o.w : 0.f;
    *(float4*)&D[off] = o;
    Ts[r][tc*4+0] = o.x; Ts[r][tc*4+1] = o.y;
    Ts[r][tc*4+2] = o.z; Ts[r][tc*4+3] = o.w;
  }
  if (by == bx) return;
  __syncthreads();
  int tc2 = t & 7, jr0 = t >> 3;
  #pragma unroll
  for (int e = 0; e < 2; e++){
    int c = jr0 + e*32;
    float4 o;
    o.x = Ts[tc2*4+0][c];
    o.y = Ts[tc2*4+1][c];
    o.z = Ts[tc2*4+2][c];
    o.w = Ts[tc2*4+3][c];
    *(float4*)&D[(size_t)(j0 + c) * N + i0 + tc2*4] = o;
  }
}

// ---------------- top-21 per row: 1 wave, all-register ----------------
__global__ __launch_bounds__(64) void topk_kernel(const float* __restrict__ D, int* __restrict__ T){
  int i = blockIdx.x, t = threadIdx.x;
  const float* row = D + (size_t)i * N;
  u64 key[16];
  #pragma unroll
  for (int q = 0; q < 4; q++){
    int l0 = t*4 + q*256;
    float4 f = *(const float4*)&row[l0];
    key[q*4+0] = ((u64)__float_as_uint(f.x) << 32) | (unsigned)(l0+0);
    key[q*4+1] = ((u64)__float_as_uint(f.y) << 32) | (unsigned)(l0+1);
    key[q*4+2] = ((u64)__float_as_uint(f.z) << 32) | (unsigned)(l0+2);
    key[q*4+3] = ((u64)__float_as_uint(f.w) << 32) | (unsigned)(l0+3);
  }
  for (int it = 0; it < 21; ++it){
    u64 m = key[0];
    #pragma unroll
    for (int q = 1; q < 16; q++) m = umin64(m, key[q]);
    #pragma unroll
    for (int off = 1; off < 64; off <<= 1) m = umin64(m, __shfl_xor(m, off));
    if (t == 0) T[i*21 + it] = (int)(m & 0xffffffffull);
    #pragma unroll
    for (int q = 0; q < 16; q++) if (key[q] == m) key[q] = ~0ull;
  }
}

// ---------------- reciprocal masks ----------------
__global__ __launch_bounds__(64) void recip_kernel(const int* __restrict__ T,
                                                   u64* __restrict__ Kb, u64* __restrict__ Khb){
  int i = blockIdx.x, t = threadIdx.x;
  __shared__ u64 kb[16], khb[16];
  if (t < 16){ kb[t] = 0; khb[t] = 0; }
  __syncthreads();
  if (t < 21){
    int j = T[i*21 + t];
    bool r21 = false, r11 = false;
    for (int p = 0; p < 21; p++){
      if (T[j*21 + p] == i){ r21 = true; if (p < 11) r11 = true; }
    }
    if (r21) atomicOr(&kb[j >> 6], 1ull << (j & 63));
    if (t < 11 && r11) atomicOr(&khb[j >> 6], 1ull << (j & 63));
  }
  __syncthreads();
  if (t < 16){ Kb[i*16 + t] = kb[t]; Khb[i*16 + t] = khb[t]; }
}

// ---------------- query expansion: 1 block per row, lane-parallel over neighbors ----------------
__global__ __launch_bounds__(64) void expand_kernel(const u64* __restrict__ Kb,
                                                    const u64* __restrict__ Khb,
                                                    u64* __restrict__ Eb){
  int i = blockIdx.x;
  int lane = threadIdx.x;
  __shared__ u64 er[16];
  __shared__ int js[32];
  __shared__ int njs;
  if (lane == 0) njs = 0;
  __syncthreads();
  if (lane < 16){
    u64 w = Kb[i*16 + lane];
    er[lane] = w;
    while (w){
      int bit = __ffsll((long long)w) - 1;
      w &= w - 1;
      int pos = atomicAdd(&njs, 1);
      js[pos] = lane*64 + bit;
    }
  }
  __syncthreads();
  if (lane < njs){
    int j = js[lane];
    int inter = 0, sz = 0;
    #pragma unroll
    for (int w = 0; w < 16; w++){
      u64 kh = Khb[(size_t)j*16 + w];
      u64 kw = Kb[(size_t)i*16 + w];
      inter += __popcll(kw & kh);
      sz += __popcll(kh);
    }
    if (3*inter > 2*sz){
      #pragma unroll
      for (int w = 0; w < 16; w++){
        u64 kh = Khb[(size_t)j*16 + w];
        if (kh) atomicOr(&er[w], kh);
      }
    }
  }
  __syncthreads();
  if (lane < 16) Eb[i*16 + lane] = er[lane];
}

// ---------------- V = rownorm(exp(-D0) * E) ----------------
__global__ __launch_bounds__(256) void v_kernel(const float* __restrict__ Dm,
                                                const u64* __restrict__ Eb,
                                                float* __restrict__ V){
  int i = blockIdx.x, t = threadIdx.x;
  float w[4];
  #pragma unroll
  for (int q = 0; q < 4; q++){
    int l = t + q*256;
    u64 word = Eb[i*16 + (l >> 6)];
    float e = expf(-Dm[(size_t)i * N + l]);
    w[q] = ((word >> (l & 63)) & 1ull) ? e : 0.f;
  }
  float s = w[0] + w[1] + w[2] + w[3];
  #pragma unroll
  for (int off = 32; off > 0; off >>= 1) s += __shfl_down(s, off);
  __shared__ float sm[4];
  __shared__ float stot;
  if ((t & 63) == 0) sm[t >> 6] = s;
  __syncthreads();
  if (t == 0){ float S = sm[0] + sm[1] + sm[2] + sm[3]; stot = (S == 0.f) ? 1.f : S; }
  __syncthreads();
  float denom = stot;
  #pragma unroll
  for (int q = 0; q < 4; q++){
    int l = t + q*256;
    V[(size_t)i * N + l] = w[q] / denom;
  }
}

// ---------------- Vbar[i] = mean of V over 6 nearest neighbors; fused VbS = OR of E rows ----------------
__global__ __launch_bounds__(256) void vbar_kernel(const float* __restrict__ V,
                                                   const int* __restrict__ T,
                                                   const u64* __restrict__ Eb,
                                                   float* __restrict__ Vb,
                                                   u64* __restrict__ VbS){
  int i = blockIdx.x, t = threadIdx.x;
  int t6[6];
  #pragma unroll
  for (int p = 0; p < 6; p++) t6[p] = T[i*21 + p];
  if (t < 16){
    u64 o = 0;
    #pragma unroll
    for (int p = 0; p < 6; p++) o |= Eb[(size_t)t6[p]*16 + t];
    VbS[i*16 + t] = o;
  }
  #pragma unroll
  for (int q = 0; q < 4; q++){
    int l = t + q*256;
    float s = 0.f;
    #pragma unroll
    for (int p = 0; p < 6; p++) s += V[(size_t)t6[p] * N + l];
    Vb[(size_t)i * N + l] = s / 6.0f;
  }
}

// ---------------- column-compressed Vb, atomic-free: block per column k ----------------
__global__ __launch_bounds__(256) void colbuild_kernel(const float* __restrict__ Vb,
                                                       const u64* __restrict__ VbS,
                                                       int* __restrict__ colCnt,
                                                       int* __restrict__ colJ,
                                                       float* __restrict__ colV){
  int k = blockIdx.x;
  int w = k >> 6, bshift = k & 63;
  int t = threadIdx.x;
  int lane = t & 63, wv = t >> 6;
  int cnt = 0;
  int js[4];
  #pragma unroll
  for (int e = 0; e < 4; e++){
    int j = t*4 + e;
    u64 word = VbS[(size_t)j*16 + w];
    if ((word >> bshift) & 1ull) js[cnt++] = j;
  }
  int incl = cnt;
  #pragma unroll
  for (int off = 1; off < 64; off <<= 1){
    int n = __shfl_up(incl, off);
    if (lane >= off) incl += n;
  }
  __shared__ int warpoff[4];
  if (lane == 63) warpoff[wv] = incl;
  __syncthreads();
  int wbase = 0;
  for (int v = 0; v < wv; v++) wbase += warpoff[v];
  int excl = wbase + incl - cnt;
  for (int e = 0; e < cnt; e++){
    int j = js[e];
    colJ[k*1024 + excl + e] = j;
    colV[k*1024 + excl + e] = Vb[(size_t)j*N + k];
  }
  if (t == 255) colCnt[k] = wbase + incl;
}

// ---------------- sparse jaccard: 8 LDS accumulators, barrier per 8 columns ----------------
// Column slot c=0..7 scatters to tmp[c]; each (c,j) owned by exactly one thread in a group
// -> race-free; barrier only between groups. Deterministic fixed summation order.
__global__ __launch_bounds__(256) void jac_sparse_kernel(const float* __restrict__ Vb,
                                                         const u64* __restrict__ VbS,
                                                         const int* __restrict__ colCnt,
                                                         const int* __restrict__ colJ,
                                                         const float* __restrict__ colV,
                                                         float* __restrict__ Dm){
  int i = blockIdx.x, t = threadIdx.x;
  __shared__ float viRow[N];
  __shared__ float tmp[8][N];
  __shared__ u64 sbits[16];
  __shared__ int klist[N];
  __shared__ int warpoff[4];
  __shared__ int sS;
  #pragma unroll
  for (int q = 0; q < 4; q++){
    int l = t + q*256;
    viRow[l] = Vb[(size_t)i*N + l];
    #pragma unroll
    for (int c = 0; c < 8; c++) tmp[c][l] = 0.f;
  }
  if (t < 16) sbits[t] = VbS[i*16 + t];
  __syncthreads();
  // build klist (ascending k) via scan compaction
  int lane = t & 63, wv = t >> 6;
  int cnt = 0; int ks[4];
  #pragma unroll
  for (int e = 0; e < 4; e++){
    int k = t*4 + e;
    if ((sbits[k >> 6] >> (k & 63)) & 1ull) ks[cnt++] = k;
  }
  int incl = cnt;
  #pragma unroll
  for (int off = 1; off < 64; off <<= 1){
    int n = __shfl_up(incl, off);
    if (lane >= off) incl += n;
  }
  if (lane == 63) warpoff[wv] = incl;
  __syncthreads();
  int wbase = 0;
  for (int v = 0; v < wv; v++) wbase += warpoff[v];
  int excl = wbase + incl - cnt;
  for (int e = 0; e < cnt; e++) klist[excl + e] = ks[e];
  if (t == 255) sS = wbase + incl;
  __syncthreads();
  int S = sS;
  for (int g0 = 0; g0 < S; g0 += 8){
    #pragma unroll
    for (int c = 0; c < 8; c++){
      int gi = g0 + c;
      if (gi < S){
        int k = klist[gi];
        float vik = viRow[k];
        int len = colCnt[k];
        const int*   cj = &colJ[k*1024];
        const float* cv = &colV[k*1024];
        for (int idx = t; idx < len; idx += 256){
          int j = cj[idx];
          tmp[c][j] += fminf(vik, cv[idx]);
        }
      }
    }
    __syncthreads();
  }
  #pragma unroll
  for (int q = 0; q < 4; q++){
    int l = t + q*256;
    float tm = ((tmp[0][l] + tmp[1][l]) + (tmp[2][l] + tmp[3][l]))
             + ((tmp[4][l] + tmp[5][l]) + (tmp[6][l] + tmp[7][l]));
    size_t off = (size_t)i*N + l;
    float d0 = Dm[off];
    Dm[off] = 0.7f * (1.0f - tm / (2.0f - tm)) + 0.3f * d0;
  }
}

// ---------------- dense jaccard fallback (small-workspace path) ----------------
__global__ __launch_bounds__(256) void jac_split_kernel(const float* __restrict__ Vb,
    float* __restrict__ p0, float* __restrict__ p1, int kc){
  __shared__ __align__(16) float As[32][64];
  __shared__ __align__(16) float Bs[32][64];
  int by, bx; tri_map(blockIdx.x, &by, &bx);
  int z = blockIdx.y;
  int t = threadIdx.x;
  int tx = t & 15, ty = t >> 4;
  int i0 = by * 64, j0 = bx * 64;
  int kbase = z * kc;
  int nslab = kc >> 5;
  int row0 = t >> 3, kq = t & 7;
  int sw = kq << 3;

  float4 fa0 = *(const float4*)&Vb[(size_t)(i0+row0)*N    + kbase + kq*4];
  float4 fa1 = *(const float4*)&Vb[(size_t)(i0+row0+32)*N + kbase + kq*4];
  float4 fb0 = *(const float4*)&Vb[(size_t)(j0+row0)*N    + kbase + kq*4];
  float4 fb1 = *(const float4*)&Vb[(size_t)(j0+row0+32)*N + kbase + kq*4];

  float acc[4][4] = {};
  for (int s = 0; s < nslab; s++){
    {
      float va0[4] = {fa0.x, fa0.y, fa0.z, fa0.w};
      float va1[4] = {fa1.x, fa1.y, fa1.z, fa1.w};
      float vb0[4] = {fb0.x, fb0.y, fb0.z, fb0.w};
      float vb1[4] = {fb1.x, fb1.y, fb1.z, fb1.w};
      #pragma unroll
      for (int e2 = 0; e2 < 4; e2++){
        As[kq*4+e2][row0 ^ sw]      = va0[e2];
        As[kq*4+e2][(row0+32) ^ sw] = va1[e2];
        Bs[kq*4+e2][row0 ^ sw]      = vb0[e2];
        Bs[kq*4+e2][(row0+32) ^ sw] = vb1[e2];
      }
    }
    __syncthreads();
    if (s + 1 < nslab){
      int k0 = kbase + (s+1)*32;
      fa0 = *(const float4*)&Vb[(size_t)(i0+row0)*N    + k0 + kq*4];
      fa1 = *(const float4*)&Vb[(size_t)(i0+row0+32)*N + k0 + kq*4];
      fb0 = *(const float4*)&Vb[(size_t)(j0+row0)*N    + k0 + kq*4];
      fb1 = *(const float4*)&Vb[(size_t)(j0+row0+32)*N + k0 + kq*4];
    }
    #pragma unroll
    for (int kk = 0; kk < 32; kk++){
      int swk = (kk >> 2) << 3;
      float4 a4 = *(const float4*)&As[kk][(ty*4) ^ swk];
      float4 b4 = *(const float4*)&Bs[kk][(tx*4) ^ swk];
      float av[4] = {a4.x, a4.y, a4.z, a4.w};
      float bv[4] = {b4.x, b4.y, b4.z, b4.w};
      #pragma unroll
      for (int r = 0; r < 4; r++){
        #pragma unroll
        for (int c = 0; c < 4; c++) acc[r][c] += fminf(av[r], bv[c]);
      }
    }
    __syncthreads();
  }
  float* P = (z == 0) ? p0 : p1 + (size_t)(z - 1) * N * N;
  #pragma unroll
  for (int r = 0; r < 4; r++){
    #pragma unroll
    for (int c = 0; c < 4; c++){
      int i = i0 + ty*4 + r, j = j0 + tx*4 + c;
      P[(size_t)i * N + j] = acc[r][c];
    }
  }
}

__global__ __launch_bounds__(256) void jac_combine_kernel(
    const float* __restrict__ p0, const float* __restrict__ p1,
    int nsplit, float* __restrict__ Dm){
  __shared__ float Ts[32][68];
  int by, bx; tri_map(blockIdx.x, &by, &bx);
  int h = blockIdx.y;
  int t = threadIdx.x;
  int tc = t & 15, tr = t >> 4;
  int i0 = by * 64 + h * 32, j0 = bx * 64;
  #pragma unroll
  for (int rr = 0; rr < 2; rr++){
    int r = tr*2 + rr;
    int i = i0 + r;
    size_t off = (size_t)i * N + j0 + tc*4;
    float4 s = *(const float4*)&p0[off];
    for (int z = 1; z < nsplit; z++){
      float4 q = *(const float4*)&p1[(size_t)(z-1)*N*N + off];
      s.x += q.x; s.y += q.y; s.z += q.z; s.w += q.w;
    }
    float4 d0 = *(const float4*)&Dm[off];
    float4 o;
    o.x = 0.7f * (1.0f - s.x / (2.0f - s.x)) + 0.3f * d0.x;
    o.y = 0.7f * (1.0f - s.y / (2.0f - s.y)) + 0.3f * d0.y;
    o.z = 0.7f * (1.0f - s.z / (2.0f - s.z)) + 0.3f * d0.z;
    o.w = 0.7f * (1.0f - s.w / (2.0f - s.w)) + 0.3f * d0.w;
    *(float4*)&Dm[off] = o;
    Ts[r][tc*4+0] = o.x; Ts[r][tc*4+1] = o.y;
    Ts[r][tc*4+2] = o.z; Ts[r][tc*4+3] = o.w;
  }
  if (by == bx) return;
  __syncthreads();
  int tc2 = t & 7, jr0 = t >> 3;
  #pragma unroll
  for (int e = 0; e < 2; e++){
    int c = jr0 + e*32;
    float4 o;
    o.x = Ts[tc2*4+0][c];
    o.y = Ts[tc2*4+1][c];
    o.z = Ts[tc2*4+2][c];
    o.w = Ts[tc2*4+3][c];
    *(float4*)&Dm[(size_t)(j0 + c) * N + i0 + tc2*4] = o;
  }
}

// ---------------- dist_ap / dist_an ----------------
__global__ __launch_bounds__(256) void apan_kernel(const float* __restrict__ Dm,
                                                   const int* __restrict__ tg,
                                                   float* __restrict__ ap, float* __restrict__ an){
  int i = blockIdx.x, t = threadIdx.x;
  int ti = tg[i];
  float mx = -3.402823466e38f, mn = 3.402823466e38f;
  #pragma unroll
  for (int q = 0; q < 4; q++){
    int l = t + q*256;
    float v = Dm[(size_t)i * N + l];
    if (tg[l] == ti) mx = fmaxf(mx, v); else mn = fminf(mn, v);
  }
  #pragma unroll
  for (int off = 32; off > 0; off >>= 1){
    mx = fmaxf(mx, __shfl_down(mx, off));
    mn = fminf(mn, __shfl_down(mn, off));
  }
  __shared__ float smx[4], smn[4];
  if ((t & 63) == 0){ smx[t >> 6] = mx; smn[t >> 6] = mn; }
  __syncthreads();
  if (t == 0){
    ap[i] = fmaxf(fmaxf(smx[0], smx[1]), fmaxf(smx[2], smx[3]));
    an[i] = fminf(fminf(smn[0], smn[1]), fminf(smn[2], smn[3]));
  }
}

// ---------------- loss ----------------
__global__ __launch_bounds__(256) void loss_kernel(const float* __restrict__ ap,
                                                   const float* __restrict__ an,
                                                   float* __restrict__ out){
  int t = threadIdx.x;
  float s = 0.f;
  #pragma unroll
  for (int q = 0; q < 4; q++){
    int l = t + q*256;
    s += fmaxf(ap[l] - an[l] + 0.03f, 0.f);
  }
  #pragma unroll
  for (int off = 32; off > 0; off >>= 1) s += __shfl_down(s, off);
  __shared__ float sm[4];
  if ((t & 63) == 0) sm[t >> 6] = s;
  __syncthreads();
  if (t == 0) out[0] = (sm[0] + sm[1] + sm[2] + sm[3]) / 1024.0f;
}

// ---------------- launch ----------------
static const size_t XX_OFF  = 0;          // 1024 f32
static const size_t T_OFF   = 4096;       // 1024*21 i32
static const size_t KB_OFF  = 90112;      // 1024*16 u64
static const size_t KHB_OFF = 221184;
static const size_t EB_OFF  = 352256;
static const size_t V_OFF   = 483328;     // 1024*1024 f32 (doubles as partial 0)
static const size_t VB_OFF  = 4677632;    // 1024*1024 f32
static const size_t P1_OFF  = 8871936;    // gemm partials 1..nsplit-1; later reused for sparse structs
static const size_t NN4     = 4194304;    // N*N*4 bytes
// sparse jaccard structures (temporal reuse of P1 region, after gemm_combine):
static const size_t CJ_REL   = 0;                  // colJ: 1024*1024 i32 = 4MB
static const size_t CV_REL   = 4194304;            // colV: 1024*1024 f32 = 4MB
static const size_t CC_REL   = 8388608;            // colCnt: 1024 i32 = 4KB
static const size_t VBS_REL  = 8392704;            // VbS: 1024*16 u64 = 128KB
static const size_t SPARSE_NEED = 8523776;         // CJ+CV+CC+VBS

extern "C" void kernel_launch(void* const* d_in, const int* in_sizes, int n_in,
                              void* d_out, int out_size, void* d_ws, size_t ws_size,
                              hipStream_t stream){
  const float* x  = (const float*)d_in[0];
  const int*   tg = (const int*)d_in[1];
  float* out = (float*)d_out;
  char* ws = (char*)d_ws;
  if (ws_size < P1_OFF) return;

  float* xx  = (float*)(ws + XX_OFF);
  int*   T   = (int*)(ws + T_OFF);
  u64*   Kb  = (u64*)(ws + KB_OFF);
  u64*   Khb = (u64*)(ws + KHB_OFF);
  u64*   Eb  = (u64*)(ws + EB_OFF);
  float* V   = (float*)(ws + V_OFF);
  float* Vb  = (float*)(ws + VB_OFF);

  float* dist = out + 1;
  float* ap   = out + 1 + (size_t)N*N;
  float* an   = ap + N;

  size_t avail = ws_size - P1_OFF;
  int nsplit = (avail >= 15*NN4) ? 16 : (avail >= 7*NN4) ? 8 : (avail >= 3*NN4) ? 4 : (avail >= 1*NN4) ? 2 : 1;
  float* P0 = V;                       // V buffer is free until v_kernel
  float* P1 = (float*)(ws + P1_OFF);   // gemm partials z=1..nsplit-1

  bool use_sparse = (avail >= SPARSE_NEED);
  int*   colJ   = (int*)(ws + P1_OFF + CJ_REL);
  float* colV   = (float*)(ws + P1_OFF + CV_REL);
  int*   colCnt = (int*)(ws + P1_OFF + CC_REL);
  u64*   VbS    = (u64*)(ws + P1_OFF + VBS_REL);

  rownorm_kernel     <<<N, 256, 0, stream>>>(x, xx);
  gemm_split_kernel  <<<dim3(136, nsplit), 256, 0, stream>>>(x, P0, P1, DIM/nsplit);
  gemm_combine_kernel<<<dim3(136, 2), 256, 0, stream>>>(P0, P1, nsplit, xx, dist);
  topk_kernel        <<<N, 64, 0, stream>>>(dist, T);
  recip_kernel       <<<N, 64, 0, stream>>>(T, Kb, Khb);
  expand_kernel      <<<N, 64, 0, stream>>>(Kb, Khb, Eb);
  v_kernel           <<<N, 256, 0, stream>>>(dist, Eb, V);
  if (use_sparse){
    vbar_kernel      <<<N, 256, 0, stream>>>(V, T, Eb, Vb, VbS);
    colbuild_kernel  <<<N, 256, 0, stream>>>(Vb, VbS, colCnt, colJ, colV);
    jac_sparse_kernel<<<N, 256, 0, stream>>>(Vb, VbS, colCnt, colJ, colV, dist);
  } else {
    vbar_kernel      <<<N, 256, 0, stream>>>(V, T, Eb, Vb, VbS);
    jac_split_kernel <<<dim3(136, nsplit), 256, 0, stream>>>(Vb, P0, P1, N/nsplit);
    jac_combine_kernel<<<dim3(136, 2), 256, 0, stream>>>(P0, P1, nsplit, dist);
  }
  apan_kernel        <<<N, 256, 0, stream>>>(dist, tg, ap, an);
  loss_kernel        <<<1, 256, 0, stream>>>(ap, an, out);
}

// Round 17
// 139.682 us; speedup vs baseline: 1.1661x; 1.1661x over previous
//
#include <hip/hip_runtime.h>

#define N 1024
#define DIM 2048

typedef unsigned long long u64;

__device__ __forceinline__ u64 umin64(u64 a, u64 b){ return a < b ? a : b; }

// map linear id in [0,136) to lower-triangle block coords (by >= bx), 16x16 blocks
__device__ __forceinline__ void tri_map(int lid, int* by, int* bx){
  int y = (int)((sqrtf(8.0f * lid + 1.0f) - 1.0f) * 0.5f);
  while ((y + 1) * (y + 2) / 2 <= lid) y++;
  while (y * (y + 1) / 2 > lid) y--;
  *by = y;
  *bx = lid - y * (y + 1) / 2;
}

// ---------------- row norms ----------------
__global__ __launch_bounds__(256) void rownorm_kernel(const float* __restrict__ x, float* __restrict__ xx){
  int i = blockIdx.x, t = threadIdx.x;
  const float4* row = (const float4*)(x + (size_t)i * DIM);
  float s = 0.f;
  #pragma unroll
  for (int q = 0; q < 2; q++){
    float4 v = row[t + q*256];
    s += v.x*v.x + v.y*v.y + v.z*v.z + v.w*v.w;
  }
  #pragma unroll
  for (int off = 32; off > 0; off >>= 1) s += __shfl_down(s, off);
  __shared__ float sm[4];
  if ((t & 63) == 0) sm[t >> 6] = s;
  __syncthreads();
  if (t == 0) xx[i] = sm[0] + sm[1] + sm[2] + sm[3];
}

// ---------------- x@x^T partials: tri grid, split-K, single-LDS + register prefetch ----------------
// r11-proven structure: plain __launch_bounds__(256), 4x4 tile.
__global__ __launch_bounds__(256) void gemm_split_kernel(const float* __restrict__ x,
    float* __restrict__ p0, float* __restrict__ p1, int kc){
  __shared__ __align__(16) float As[32][64];
  __shared__ __align__(16) float Bs[32][64];
  int by, bx; tri_map(blockIdx.x, &by, &bx);
  int z = blockIdx.y;
  int t = threadIdx.x;
  int tx = t & 15, ty = t >> 4;
  int i0 = by * 64, j0 = bx * 64;
  int kbase = z * kc;
  int nslab = kc >> 5;
  int row0 = t >> 3, kq = t & 7;
  int sw = kq << 3;

  float4 fa0 = *(const float4*)&x[(size_t)(i0+row0)*DIM    + kbase + kq*4];
  float4 fa1 = *(const float4*)&x[(size_t)(i0+row0+32)*DIM + kbase + kq*4];
  float4 fb0 = *(const float4*)&x[(size_t)(j0+row0)*DIM    + kbase + kq*4];
  float4 fb1 = *(const float4*)&x[(size_t)(j0+row0+32)*DIM + kbase + kq*4];

  float acc[4][4] = {};
  for (int s = 0; s < nslab; s++){
    {
      float va0[4] = {fa0.x, fa0.y, fa0.z, fa0.w};
      float va1[4] = {fa1.x, fa1.y, fa1.z, fa1.w};
      float vb0[4] = {fb0.x, fb0.y, fb0.z, fb0.w};
      float vb1[4] = {fb1.x, fb1.y, fb1.z, fb1.w};
      #pragma unroll
      for (int e2 = 0; e2 < 4; e2++){
        As[kq*4+e2][row0 ^ sw]      = va0[e2];
        As[kq*4+e2][(row0+32) ^ sw] = va1[e2];
        Bs[kq*4+e2][row0 ^ sw]      = vb0[e2];
        Bs[kq*4+e2][(row0+32) ^ sw] = vb1[e2];
      }
    }
    __syncthreads();
    if (s + 1 < nslab){
      int k0 = kbase + (s+1)*32;
      fa0 = *(const float4*)&x[(size_t)(i0+row0)*DIM    + k0 + kq*4];
      fa1 = *(const float4*)&x[(size_t)(i0+row0+32)*DIM + k0 + kq*4];
      fb0 = *(const float4*)&x[(size_t)(j0+row0)*DIM    + k0 + kq*4];
      fb1 = *(const float4*)&x[(size_t)(j0+row0+32)*DIM + k0 + kq*4];
    }
    #pragma unroll
    for (int kk = 0; kk < 32; kk++){
      int swk = (kk >> 2) << 3;
      float4 a4 = *(const float4*)&As[kk][(ty*4) ^ swk];
      float4 b4 = *(const float4*)&Bs[kk][(tx*4) ^ swk];
      float av[4] = {a4.x, a4.y, a4.z, a4.w};
      float bv[4] = {b4.x, b4.y, b4.z, b4.w};
      #pragma unroll
      for (int r = 0; r < 4; r++){
        #pragma unroll
        for (int c = 0; c < 4; c++) acc[r][c] = fmaf(av[r], bv[c], acc[r][c]);
      }
    }
    __syncthreads();
  }
  float* P = (z == 0) ? p0 : p1 + (size_t)(z - 1) * N * N;
  #pragma unroll
  for (int r = 0; r < 4; r++){
    #pragma unroll
    for (int c = 0; c < 4; c++){
      int i = i0 + ty*4 + r, j = j0 + tx*4 + c;
      P[(size_t)i * N + j] = acc[r][c];
    }
  }
}

// ---------------- combine -> D0 = clamp(xx_i+xx_j-2*dot,0), mirror; 2 row-halves/tile ----------------
__global__ __launch_bounds__(256) void gemm_combine_kernel(
    const float* __restrict__ p0, const float* __restrict__ p1,
    int nsplit, const float* __restrict__ xx, float* __restrict__ D){
  __shared__ float Ts[32][68];
  int by, bx; tri_map(blockIdx.x, &by, &bx);
  int h = blockIdx.y;
  int t = threadIdx.x;
  int tc = t & 15, tr = t >> 4;
  int i0 = by * 64 + h * 32, j0 = bx * 64;
  float4 xj = *(const float4*)&xx[j0 + tc*4];
  #pragma unroll
  for (int rr = 0; rr < 2; rr++){
    int r = tr*2 + rr;
    int i = i0 + r;
    size_t off = (size_t)i * N + j0 + tc*4;
    float4 s = *(const float4*)&p0[off];
    for (int z = 1; z < nsplit; z++){
      float4 q = *(const float4*)&p1[(size_t)(z-1)*N*N + off];
      s.x += q.x; s.y += q.y; s.z += q.z; s.w += q.w;
    }
    float xxi = xx[i];
    float4 o;
    o.x = xxi + xj.x - 2.0f*s.x; o.x = (o.x > 0.f) ? o.x : 0.f;
    o.y = xxi + xj.y - 2.0f*s.y; o.y = (o.y > 0.f) ? o.y : 0.f;
    o.z = xxi + xj.z - 2.0f*s.z; o.z = (o.z > 0.f) ? o.z : 0.f;
    o.w = xxi + xj.w - 2.0f*s.w; o.w = (o.w > 0.f) ? o.w : 0.f;
    *(float4*)&D[off] = o;
    Ts[r][tc*4+0] = o.x; Ts[r][tc*4+1] = o.y;
    Ts[r][tc*4+2] = o.z; Ts[r][tc*4+3] = o.w;
  }
  if (by == bx) return;
  __syncthreads();
  int tc2 = t & 7, jr0 = t >> 3;
  #pragma unroll
  for (int e = 0; e < 2; e++){
    int c = jr0 + e*32;
    float4 o;
    o.x = Ts[tc2*4+0][c];
    o.y = Ts[tc2*4+1][c];
    o.z = Ts[tc2*4+2][c];
    o.w = Ts[tc2*4+3][c];
    *(float4*)&D[(size_t)(j0 + c) * N + i0 + tc2*4] = o;
  }
}

// ---------------- top-21 per row: 1 wave, all-register ----------------
__global__ __launch_bounds__(64) void topk_kernel(const float* __restrict__ D, int* __restrict__ T){
  int i = blockIdx.x, t = threadIdx.x;
  const float* row = D + (size_t)i * N;
  u64 key[16];
  #pragma unroll
  for (int q = 0; q < 4; q++){
    int l0 = t*4 + q*256;
    float4 f = *(const float4*)&row[l0];
    key[q*4+0] = ((u64)__float_as_uint(f.x) << 32) | (unsigned)(l0+0);
    key[q*4+1] = ((u64)__float_as_uint(f.y) << 32) | (unsigned)(l0+1);
    key[q*4+2] = ((u64)__float_as_uint(f.z) << 32) | (unsigned)(l0+2);
    key[q*4+3] = ((u64)__float_as_uint(f.w) << 32) | (unsigned)(l0+3);
  }
  for (int it = 0; it < 21; ++it){
    u64 m = key[0];
    #pragma unroll
    for (int q = 1; q < 16; q++) m = umin64(m, key[q]);
    #pragma unroll
    for (int off = 1; off < 64; off <<= 1) m = umin64(m, __shfl_xor(m, off));
    if (t == 0) T[i*21 + it] = (int)(m & 0xffffffffull);
    #pragma unroll
    for (int q = 0; q < 16; q++) if (key[q] == m) key[q] = ~0ull;
  }
}

// ---------------- reciprocal masks ----------------
__global__ __launch_bounds__(64) void recip_kernel(const int* __restrict__ T,
                                                   u64* __restrict__ Kb, u64* __restrict__ Khb){
  int i = blockIdx.x, t = threadIdx.x;
  __shared__ u64 kb[16], khb[16];
  if (t < 16){ kb[t] = 0; khb[t] = 0; }
  __syncthreads();
  if (t < 21){
    int j = T[i*21 + t];
    bool r21 = false, r11 = false;
    for (int p = 0; p < 21; p++){
      if (T[j*21 + p] == i){ r21 = true; if (p < 11) r11 = true; }
    }
    if (r21) atomicOr(&kb[j >> 6], 1ull << (j & 63));
    if (t < 11 && r11) atomicOr(&khb[j >> 6], 1ull << (j & 63));
  }
  __syncthreads();
  if (t < 16){ Kb[i*16 + t] = kb[t]; Khb[i*16 + t] = khb[t]; }
}

// ---------------- query expansion: 1 block per row, lane-parallel over neighbors ----------------
__global__ __launch_bounds__(64) void expand_kernel(const u64* __restrict__ Kb,
                                                    const u64* __restrict__ Khb,
                                                    u64* __restrict__ Eb){
  int i = blockIdx.x;
  int lane = threadIdx.x;
  __shared__ u64 er[16];
  __shared__ int js[32];
  __shared__ int njs;
  if (lane == 0) njs = 0;
  __syncthreads();
  if (lane < 16){
    u64 w = Kb[i*16 + lane];
    er[lane] = w;
    while (w){
      int bit = __ffsll((long long)w) - 1;
      w &= w - 1;
      int pos = atomicAdd(&njs, 1);
      js[pos] = lane*64 + bit;
    }
  }
  __syncthreads();
  if (lane < njs){
    int j = js[lane];
    int inter = 0, sz = 0;
    #pragma unroll
    for (int w = 0; w < 16; w++){
      u64 kh = Khb[(size_t)j*16 + w];
      u64 kw = Kb[(size_t)i*16 + w];
      inter += __popcll(kw & kh);
      sz += __popcll(kh);
    }
    if (3*inter > 2*sz){
      #pragma unroll
      for (int w = 0; w < 16; w++){
        u64 kh = Khb[(size_t)j*16 + w];
        if (kh) atomicOr(&er[w], kh);
      }
    }
  }
  __syncthreads();
  if (lane < 16) Eb[i*16 + lane] = er[lane];
}

// ---------------- V = rownorm(exp(-D0) * E) ----------------
__global__ __launch_bounds__(256) void v_kernel(const float* __restrict__ Dm,
                                                const u64* __restrict__ Eb,
                                                float* __restrict__ V){
  int i = blockIdx.x, t = threadIdx.x;
  float w[4];
  #pragma unroll
  for (int q = 0; q < 4; q++){
    int l = t + q*256;
    u64 word = Eb[i*16 + (l >> 6)];
    float e = expf(-Dm[(size_t)i * N + l]);
    w[q] = ((word >> (l & 63)) & 1ull) ? e : 0.f;
  }
  float s = w[0] + w[1] + w[2] + w[3];
  #pragma unroll
  for (int off = 32; off > 0; off >>= 1) s += __shfl_down(s, off);
  __shared__ float sm[4];
  __shared__ float stot;
  if ((t & 63) == 0) sm[t >> 6] = s;
  __syncthreads();
  if (t == 0){ float S = sm[0] + sm[1] + sm[2] + sm[3]; stot = (S == 0.f) ? 1.f : S; }
  __syncthreads();
  float denom = stot;
  #pragma unroll
  for (int q = 0; q < 4; q++){
    int l = t + q*256;
    V[(size_t)i * N + l] = w[q] / denom;
  }
}

// ---------------- Vbar[i] = mean of V over 6 nearest neighbors; fused VbS = OR of E rows ----------------
__global__ __launch_bounds__(256) void vbar_kernel(const float* __restrict__ V,
                                                   const int* __restrict__ T,
                                                   const u64* __restrict__ Eb,
                                                   float* __restrict__ Vb,
                                                   u64* __restrict__ VbS){
  int i = blockIdx.x, t = threadIdx.x;
  int t6[6];
  #pragma unroll
  for (int p = 0; p < 6; p++) t6[p] = T[i*21 + p];
  if (t < 16){
    u64 o = 0;
    #pragma unroll
    for (int p = 0; p < 6; p++) o |= Eb[(size_t)t6[p]*16 + t];
    VbS[i*16 + t] = o;
  }
  #pragma unroll
  for (int q = 0; q < 4; q++){
    int l = t + q*256;
    float s = 0.f;
    #pragma unroll
    for (int p = 0; p < 6; p++) s += V[(size_t)t6[p] * N + l];
    Vb[(size_t)i * N + l] = s / 6.0f;
  }
}

// ---------------- column-compressed Vb, atomic-free: block per column k ----------------
__global__ __launch_bounds__(256) void colbuild_kernel(const float* __restrict__ Vb,
                                                       const u64* __restrict__ VbS,
                                                       int* __restrict__ colCnt,
                                                       int* __restrict__ colJ,
                                                       float* __restrict__ colV){
  int k = blockIdx.x;
  int w = k >> 6, bshift = k & 63;
  int t = threadIdx.x;
  int lane = t & 63, wv = t >> 6;
  int cnt = 0;
  int js[4];
  #pragma unroll
  for (int e = 0; e < 4; e++){
    int j = t*4 + e;
    u64 word = VbS[(size_t)j*16 + w];
    if ((word >> bshift) & 1ull) js[cnt++] = j;
  }
  int incl = cnt;
  #pragma unroll
  for (int off = 1; off < 64; off <<= 1){
    int n = __shfl_up(incl, off);
    if (lane >= off) incl += n;
  }
  __shared__ int warpoff[4];
  if (lane == 63) warpoff[wv] = incl;
  __syncthreads();
  int wbase = 0;
  for (int v = 0; v < wv; v++) wbase += warpoff[v];
  int excl = wbase + incl - cnt;
  for (int e = 0; e < cnt; e++){
    int j = js[e];
    colJ[k*1024 + excl + e] = j;
    colV[k*1024 + excl + e] = Vb[(size_t)j*N + k];
  }
  if (t == 255) colCnt[k] = wbase + incl;
}

// ---------------- sparse jaccard: 4 LDS accumulators, barrier per 4 columns (r15-proven) ----------
__global__ __launch_bounds__(256) void jac_sparse_kernel(const float* __restrict__ Vb,
                                                         const u64* __restrict__ VbS,
                                                         const int* __restrict__ colCnt,
                                                         const int* __restrict__ colJ,
                                                         const float* __restrict__ colV,
                                                         float* __restrict__ Dm){
  int i = blockIdx.x, t = threadIdx.x;
  __shared__ float viRow[N];
  __shared__ float tmp[4][N];
  __shared__ u64 sbits[16];
  __shared__ int klist[N];
  __shared__ int warpoff[4];
  __shared__ int sS;
  #pragma unroll
  for (int q = 0; q < 4; q++){
    int l = t + q*256;
    viRow[l] = Vb[(size_t)i*N + l];
    tmp[0][l] = 0.f; tmp[1][l] = 0.f; tmp[2][l] = 0.f; tmp[3][l] = 0.f;
  }
  if (t < 16) sbits[t] = VbS[i*16 + t];
  __syncthreads();
  // build klist (ascending k) via scan compaction
  int lane = t & 63, wv = t >> 6;
  int cnt = 0; int ks[4];
  #pragma unroll
  for (int e = 0; e < 4; e++){
    int k = t*4 + e;
    if ((sbits[k >> 6] >> (k & 63)) & 1ull) ks[cnt++] = k;
  }
  int incl = cnt;
  #pragma unroll
  for (int off = 1; off < 64; off <<= 1){
    int n = __shfl_up(incl, off);
    if (lane >= off) incl += n;
  }
  if (lane == 63) warpoff[wv] = incl;
  __syncthreads();
  int wbase = 0;
  for (int v = 0; v < wv; v++) wbase += warpoff[v];
  int excl = wbase + incl - cnt;
  for (int e = 0; e < cnt; e++) klist[excl + e] = ks[e];
  if (t == 255) sS = wbase + incl;
  __syncthreads();
  int S = sS;
  for (int g0 = 0; g0 < S; g0 += 4){
    #pragma unroll
    for (int c = 0; c < 4; c++){
      int gi = g0 + c;
      if (gi < S){
        int k = klist[gi];
        float vik = viRow[k];
        int len = colCnt[k];
        const int*   cj = &colJ[k*1024];
        const float* cv = &colV[k*1024];
        for (int idx = t; idx < len; idx += 256){
          int j = cj[idx];
          tmp[c][j] += fminf(vik, cv[idx]);
        }
      }
    }
    __syncthreads();
  }
  #pragma unroll
  for (int q = 0; q < 4; q++){
    int l = t + q*256;
    float tm = (tmp[0][l] + tmp[1][l]) + (tmp[2][l] + tmp[3][l]);
    size_t off = (size_t)i*N + l;
    float d0 = Dm[off];
    Dm[off] = 0.7f * (1.0f - tm / (2.0f - tm)) + 0.3f * d0;
  }
}

// ---------------- dense jaccard fallback (small-workspace path) ----------------
__global__ __launch_bounds__(256) void jac_split_kernel(const float* __restrict__ Vb,
    float* __restrict__ p0, float* __restrict__ p1, int kc){
  __shared__ __align__(16) float As[32][64];
  __shared__ __align__(16) float Bs[32][64];
  int by, bx; tri_map(blockIdx.x, &by, &bx);
  int z = blockIdx.y;
  int t = threadIdx.x;
  int tx = t & 15, ty = t >> 4;
  int i0 = by * 64, j0 = bx * 64;
  int kbase = z * kc;
  int nslab = kc >> 5;
  int row0 = t >> 3, kq = t & 7;
  int sw = kq << 3;

  float4 fa0 = *(const float4*)&Vb[(size_t)(i0+row0)*N    + kbase + kq*4];
  float4 fa1 = *(const float4*)&Vb[(size_t)(i0+row0+32)*N + kbase + kq*4];
  float4 fb0 = *(const float4*)&Vb[(size_t)(j0+row0)*N    + kbase + kq*4];
  float4 fb1 = *(const float4*)&Vb[(size_t)(j0+row0+32)*N + kbase + kq*4];

  float acc[4][4] = {};
  for (int s = 0; s < nslab; s++){
    {
      float va0[4] = {fa0.x, fa0.y, fa0.z, fa0.w};
      float va1[4] = {fa1.x, fa1.y, fa1.z, fa1.w};
      float vb0[4] = {fb0.x, fb0.y, fb0.z, fb0.w};
      float vb1[4] = {fb1.x, fb1.y, fb1.z, fb1.w};
      #pragma unroll
      for (int e2 = 0; e2 < 4; e2++){
        As[kq*4+e2][row0 ^ sw]      = va0[e2];
        As[kq*4+e2][(row0+32) ^ sw] = va1[e2];
        Bs[kq*4+e2][row0 ^ sw]      = vb0[e2];
        Bs[kq*4+e2][(row0+32) ^ sw] = vb1[e2];
      }
    }
    __syncthreads();
    if (s + 1 < nslab){
      int k0 = kbase + (s+1)*32;
      fa0 = *(const float4*)&Vb[(size_t)(i0+row0)*N    + k0 + kq*4];
      fa1 = *(const float4*)&Vb[(size_t)(i0+row0+32)*N + k0 + kq*4];
      fb0 = *(const float4*)&Vb[(size_t)(j0+row0)*N    + k0 + kq*4];
      fb1 = *(const float4*)&Vb[(size_t)(j0+row0+32)*N + k0 + kq*4];
    }
    #pragma unroll
    for (int kk = 0; kk < 32; kk++){
      int swk = (kk >> 2) << 3;
      float4 a4 = *(const float4*)&As[kk][(ty*4) ^ swk];
      float4 b4 = *(const float4*)&Bs[kk][(tx*4) ^ swk];
      float av[4] = {a4.x, a4.y, a4.z, a4.w};
      float bv[4] = {b4.x, b4.y, b4.z, b4.w};
      #pragma unroll
      for (int r = 0; r < 4; r++){
        #pragma unroll
        for (int c = 0; c < 4; c++) acc[r][c] += fminf(av[r], bv[c]);
      }
    }
    __syncthreads();
  }
  float* P = (z == 0) ? p0 : p1 + (size_t)(z - 1) * N * N;
  #pragma unroll
  for (int r = 0; r < 4; r++){
    #pragma unroll
    for (int c = 0; c < 4; c++){
      int i = i0 + ty*4 + r, j = j0 + tx*4 + c;
      P[(size_t)i * N + j] = acc[r][c];
    }
  }
}

__global__ __launch_bounds__(256) void jac_combine_kernel(
    const float* __restrict__ p0, const float* __restrict__ p1,
    int nsplit, float* __restrict__ Dm){
  __shared__ float Ts[32][68];
  int by, bx; tri_map(blockIdx.x, &by, &bx);
  int h = blockIdx.y;
  int t = threadIdx.x;
  int tc = t & 15, tr = t >> 4;
  int i0 = by * 64 + h * 32, j0 = bx * 64;
  #pragma unroll
  for (int rr = 0; rr < 2; rr++){
    int r = tr*2 + rr;
    int i = i0 + r;
    size_t off = (size_t)i * N + j0 + tc*4;
    float4 s = *(const float4*)&p0[off];
    for (int z = 1; z < nsplit; z++){
      float4 q = *(const float4*)&p1[(size_t)(z-1)*N*N + off];
      s.x += q.x; s.y += q.y; s.z += q.z; s.w += q.w;
    }
    float4 d0 = *(const float4*)&Dm[off];
    float4 o;
    o.x = 0.7f * (1.0f - s.x / (2.0f - s.x)) + 0.3f * d0.x;
    o.y = 0.7f * (1.0f - s.y / (2.0f - s.y)) + 0.3f * d0.y;
    o.z = 0.7f * (1.0f - s.z / (2.0f - s.z)) + 0.3f * d0.z;
    o.w = 0.7f * (1.0f - s.w / (2.0f - s.w)) + 0.3f * d0.w;
    *(float4*)&Dm[off] = o;
    Ts[r][tc*4+0] = o.x; Ts[r][tc*4+1] = o.y;
    Ts[r][tc*4+2] = o.z; Ts[r][tc*4+3] = o.w;
  }
  if (by == bx) return;
  __syncthreads();
  int tc2 = t & 7, jr0 = t >> 3;
  #pragma unroll
  for (int e = 0; e < 2; e++){
    int c = jr0 + e*32;
    float4 o;
    o.x = Ts[tc2*4+0][c];
    o.y = Ts[tc2*4+1][c];
    o.z = Ts[tc2*4+2][c];
    o.w = Ts[tc2*4+3][c];
    *(float4*)&Dm[(size_t)(j0 + c) * N + i0 + tc2*4] = o;
  }
}

// ---------------- dist_ap / dist_an ----------------
__global__ __launch_bounds__(256) void apan_kernel(const float* __restrict__ Dm,
                                                   const int* __restrict__ tg,
                                                   float* __restrict__ ap, float* __restrict__ an){
  int i = blockIdx.x, t = threadIdx.x;
  int ti = tg[i];
  float mx = -3.402823466e38f, mn = 3.402823466e38f;
  #pragma unroll
  for (int q = 0; q < 4; q++){
    int l = t + q*256;
    float v = Dm[(size_t)i * N + l];
    if (tg[l] == ti) mx = fmaxf(mx, v); else mn = fminf(mn, v);
  }
  #pragma unroll
  for (int off = 32; off > 0; off >>= 1){
    mx = fmaxf(mx, __shfl_down(mx, off));
    mn = fminf(mn, __shfl_down(mn, off));
  }
  __shared__ float smx[4], smn[4];
  if ((t & 63) == 0){ smx[t >> 6] = mx; smn[t >> 6] = mn; }
  __syncthreads();
  if (t == 0){
    ap[i] = fmaxf(fmaxf(smx[0], smx[1]), fmaxf(smx[2], smx[3]));
    an[i] = fminf(fminf(smn[0], smn[1]), fminf(smn[2], smn[3]));
  }
}

// ---------------- loss ----------------
__global__ __launch_bounds__(256) void loss_kernel(const float* __restrict__ ap,
                                                   const float* __restrict__ an,
                                                   float* __restrict__ out){
  int t = threadIdx.x;
  float s = 0.f;
  #pragma unroll
  for (int q = 0; q < 4; q++){
    int l = t + q*256;
    s += fmaxf(ap[l] - an[l] + 0.03f, 0.f);
  }
  #pragma unroll
  for (int off = 32; off > 0; off >>= 1) s += __shfl_down(s, off);
  __shared__ float sm[4];
  if ((t & 63) == 0) sm[t >> 6] = s;
  __syncthreads();
  if (t == 0) out[0] = (sm[0] + sm[1] + sm[2] + sm[3]) / 1024.0f;
}

// ---------------- launch ----------------
static const size_t XX_OFF  = 0;          // 1024 f32
static const size_t T_OFF   = 4096;       // 1024*21 i32
static const size_t KB_OFF  = 90112;      // 1024*16 u64
static const size_t KHB_OFF = 221184;
static const size_t EB_OFF  = 352256;
static const size_t V_OFF   = 483328;     // 1024*1024 f32 (doubles as partial 0)
static const size_t VB_OFF  = 4677632;    // 1024*1024 f32
static const size_t P1_OFF  = 8871936;    // gemm partials 1..nsplit-1; later reused for sparse structs
static const size_t NN4     = 4194304;    // N*N*4 bytes
// sparse jaccard structures (temporal reuse of P1 region, after gemm_combine):
static const size_t CJ_REL   = 0;                  // colJ: 1024*1024 i32 = 4MB
static const size_t CV_REL   = 4194304;            // colV: 1024*1024 f32 = 4MB
static const size_t CC_REL   = 8388608;            // colCnt: 1024 i32 = 4KB
static const size_t VBS_REL  = 8392704;            // VbS: 1024*16 u64 = 128KB
static const size_t SPARSE_NEED = 8523776;         // CJ+CV+CC+VBS

extern "C" void kernel_launch(void* const* d_in, const int* in_sizes, int n_in,
                              void* d_out, int out_size, void* d_ws, size_t ws_size,
                              hipStream_t stream){
  const float* x  = (const float*)d_in[0];
  const int*   tg = (const int*)d_in[1];
  float* out = (float*)d_out;
  char* ws = (char*)d_ws;
  if (ws_size < P1_OFF) return;

  float* xx  = (float*)(ws + XX_OFF);
  int*   T   = (int*)(ws + T_OFF);
  u64*   Kb  = (u64*)(ws + KB_OFF);
  u64*   Khb = (u64*)(ws + KHB_OFF);
  u64*   Eb  = (u64*)(ws + EB_OFF);
  float* V   = (float*)(ws + V_OFF);
  float* Vb  = (float*)(ws + VB_OFF);

  float* dist = out + 1;
  float* ap   = out + 1 + (size_t)N*N;
  float* an   = ap + N;

  size_t avail = ws_size - P1_OFF;
  int nsplit = (avail >= 15*NN4) ? 16 : (avail >= 7*NN4) ? 8 : (avail >= 3*NN4) ? 4 : (avail >= 1*NN4) ? 2 : 1;
  float* P0 = V;                       // V buffer is free until v_kernel
  float* P1 = (float*)(ws + P1_OFF);   // gemm partials z=1..nsplit-1

  bool use_sparse = (avail >= SPARSE_NEED);
  int*   colJ   = (int*)(ws + P1_OFF + CJ_REL);
  float* colV   = (float*)(ws + P1_OFF + CV_REL);
  int*   colCnt = (int*)(ws + P1_OFF + CC_REL);
  u64*   VbS    = (u64*)(ws + P1_OFF + VBS_REL);

  rownorm_kernel     <<<N, 256, 0, stream>>>(x, xx);
  gemm_split_kernel  <<<dim3(136, nsplit), 256, 0, stream>>>(x, P0, P1, DIM/nsplit);
  gemm_combine_kernel<<<dim3(136, 2), 256, 0, stream>>>(P0, P1, nsplit, xx, dist);
  topk_kernel        <<<N, 64, 0, stream>>>(dist, T);
  recip_kernel       <<<N, 64, 0, stream>>>(T, Kb, Khb);
  expand_kernel      <<<N, 64, 0, stream>>>(Kb, Khb, Eb);
  v_kernel           <<<N, 256, 0, stream>>>(dist, Eb, V);
  if (use_sparse){
    vbar_kernel      <<<N, 256, 0, stream>>>(V, T, Eb, Vb, VbS);
    colbuild_kernel  <<<N, 256, 0, stream>>>(Vb, VbS, colCnt, colJ, colV);
    jac_sparse_kernel<<<N, 256, 0, stream>>>(Vb, VbS, colCnt, colJ, colV, dist);
  } else {
    vbar_kernel      <<<N, 256, 0, stream>>>(V, T, Eb, Vb, VbS);
    jac_split_kernel <<<dim3(136, nsplit), 256, 0, stream>>>(Vb, P0, P1, N/nsplit);
    jac_combine_kernel<<<dim3(136, 2), 256, 0, stream>>>(P0, P1, nsplit, dist);
  }
  apan_kernel        <<<N, 256, 0, stream>>>(dist, tg, ap, an);
  loss_kernel        <<<1, 256, 0, stream>>>(ap, an, out);
}

// Round 18
// 134.862 us; speedup vs baseline: 1.2078x; 1.0357x over previous
//
#include <hip/hip_runtime.h>

#define N 1024
#define DIM 2048

typedef unsigned long long u64;

__device__ __forceinline__ u64 umin64(u64 a, u64 b){ return a < b ? a : b; }

// map linear id in [0,136) to lower-triangle block coords (by >= bx), 16x16 blocks
__device__ __forceinline__ void tri_map(int lid, int* by, int* bx){
  int y = (int)((sqrtf(8.0f * lid + 1.0f) - 1.0f) * 0.5f);
  while ((y + 1) * (y + 2) / 2 <= lid) y++;
  while (y * (y + 1) / 2 > lid) y--;
  *by = y;
  *bx = lid - y * (y + 1) / 2;
}

// ---------------- row norms ----------------
__global__ __launch_bounds__(256) void rownorm_kernel(const float* __restrict__ x, float* __restrict__ xx){
  int i = blockIdx.x, t = threadIdx.x;
  const float4* row = (const float4*)(x + (size_t)i * DIM);
  float s = 0.f;
  #pragma unroll
  for (int q = 0; q < 2; q++){
    float4 v = row[t + q*256];
    s += v.x*v.x + v.y*v.y + v.z*v.z + v.w*v.w;
  }
  #pragma unroll
  for (int off = 32; off > 0; off >>= 1) s += __shfl_down(s, off);
  __shared__ float sm[4];
  if ((t & 63) == 0) sm[t >> 6] = s;
  __syncthreads();
  if (t == 0) xx[i] = sm[0] + sm[1] + sm[2] + sm[3];
}

// ---------------- x@x^T partials: tri grid, split-K, single-LDS + register prefetch ----------------
// r11-proven structure: plain __launch_bounds__(256), 4x4 tile. nsplit capped at 8:
// 16 made gemm_combine's partial traffic dominate (r17: +3.4 us vs r15).
__global__ __launch_bounds__(256) void gemm_split_kernel(const float* __restrict__ x,
    float* __restrict__ p0, float* __restrict__ p1, int kc){
  __shared__ __align__(16) float As[32][64];
  __shared__ __align__(16) float Bs[32][64];
  int by, bx; tri_map(blockIdx.x, &by, &bx);
  int z = blockIdx.y;
  int t = threadIdx.x;
  int tx = t & 15, ty = t >> 4;
  int i0 = by * 64, j0 = bx * 64;
  int kbase = z * kc;
  int nslab = kc >> 5;
  int row0 = t >> 3, kq = t & 7;
  int sw = kq << 3;

  float4 fa0 = *(const float4*)&x[(size_t)(i0+row0)*DIM    + kbase + kq*4];
  float4 fa1 = *(const float4*)&x[(size_t)(i0+row0+32)*DIM + kbase + kq*4];
  float4 fb0 = *(const float4*)&x[(size_t)(j0+row0)*DIM    + kbase + kq*4];
  float4 fb1 = *(const float4*)&x[(size_t)(j0+row0+32)*DIM + kbase + kq*4];

  float acc[4][4] = {};
  for (int s = 0; s < nslab; s++){
    {
      float va0[4] = {fa0.x, fa0.y, fa0.z, fa0.w};
      float va1[4] = {fa1.x, fa1.y, fa1.z, fa1.w};
      float vb0[4] = {fb0.x, fb0.y, fb0.z, fb0.w};
      float vb1[4] = {fb1.x, fb1.y, fb1.z, fb1.w};
      #pragma unroll
      for (int e2 = 0; e2 < 4; e2++){
        As[kq*4+e2][row0 ^ sw]      = va0[e2];
        As[kq*4+e2][(row0+32) ^ sw] = va1[e2];
        Bs[kq*4+e2][row0 ^ sw]      = vb0[e2];
        Bs[kq*4+e2][(row0+32) ^ sw] = vb1[e2];
      }
    }
    __syncthreads();
    if (s + 1 < nslab){
      int k0 = kbase + (s+1)*32;
      fa0 = *(const float4*)&x[(size_t)(i0+row0)*DIM    + k0 + kq*4];
      fa1 = *(const float4*)&x[(size_t)(i0+row0+32)*DIM + k0 + kq*4];
      fb0 = *(const float4*)&x[(size_t)(j0+row0)*DIM    + k0 + kq*4];
      fb1 = *(const float4*)&x[(size_t)(j0+row0+32)*DIM + k0 + kq*4];
    }
    #pragma unroll
    for (int kk = 0; kk < 32; kk++){
      int swk = (kk >> 2) << 3;
      float4 a4 = *(const float4*)&As[kk][(ty*4) ^ swk];
      float4 b4 = *(const float4*)&Bs[kk][(tx*4) ^ swk];
      float av[4] = {a4.x, a4.y, a4.z, a4.w};
      float bv[4] = {b4.x, b4.y, b4.z, b4.w};
      #pragma unroll
      for (int r = 0; r < 4; r++){
        #pragma unroll
        for (int c = 0; c < 4; c++) acc[r][c] = fmaf(av[r], bv[c], acc[r][c]);
      }
    }
    __syncthreads();
  }
  float* P = (z == 0) ? p0 : p1 + (size_t)(z - 1) * N * N;
  #pragma unroll
  for (int r = 0; r < 4; r++){
    #pragma unroll
    for (int c = 0; c < 4; c++){
      int i = i0 + ty*4 + r, j = j0 + tx*4 + c;
      P[(size_t)i * N + j] = acc[r][c];
    }
  }
}

// ---------------- combine -> D0 = clamp(xx_i+xx_j-2*dot,0), mirror; 2 row-halves/tile ----------------
__global__ __launch_bounds__(256) void gemm_combine_kernel(
    const float* __restrict__ p0, const float* __restrict__ p1,
    int nsplit, const float* __restrict__ xx, float* __restrict__ D){
  __shared__ float Ts[32][68];
  int by, bx; tri_map(blockIdx.x, &by, &bx);
  int h = blockIdx.y;
  int t = threadIdx.x;
  int tc = t & 15, tr = t >> 4;
  int i0 = by * 64 + h * 32, j0 = bx * 64;
  float4 xj = *(const float4*)&xx[j0 + tc*4];
  #pragma unroll
  for (int rr = 0; rr < 2; rr++){
    int r = tr*2 + rr;
    int i = i0 + r;
    size_t off = (size_t)i * N + j0 + tc*4;
    float4 s = *(const float4*)&p0[off];
    for (int z = 1; z < nsplit; z++){
      float4 q = *(const float4*)&p1[(size_t)(z-1)*N*N + off];
      s.x += q.x; s.y += q.y; s.z += q.z; s.w += q.w;
    }
    float xxi = xx[i];
    float4 o;
    o.x = xxi + xj.x - 2.0f*s.x; o.x = (o.x > 0.f) ? o.x : 0.f;
    o.y = xxi + xj.y - 2.0f*s.y; o.y = (o.y > 0.f) ? o.y : 0.f;
    o.z = xxi + xj.z - 2.0f*s.z; o.z = (o.z > 0.f) ? o.z : 0.f;
    o.w = xxi + xj.w - 2.0f*s.w; o.w = (o.w > 0.f) ? o.w : 0.f;
    *(float4*)&D[off] = o;
    Ts[r][tc*4+0] = o.x; Ts[r][tc*4+1] = o.y;
    Ts[r][tc*4+2] = o.z; Ts[r][tc*4+3] = o.w;
  }
  if (by == bx) return;
  __syncthreads();
  int tc2 = t & 7, jr0 = t >> 3;
  #pragma unroll
  for (int e = 0; e < 2; e++){
    int c = jr0 + e*32;
    float4 o;
    o.x = Ts[tc2*4+0][c];
    o.y = Ts[tc2*4+1][c];
    o.z = Ts[tc2*4+2][c];
    o.w = Ts[tc2*4+3][c];
    *(float4*)&D[(size_t)(j0 + c) * N + i0 + tc2*4] = o;
  }
}

// ---------------- top-21 per row: 1 wave, all-register ----------------
__global__ __launch_bounds__(64) void topk_kernel(const float* __restrict__ D, int* __restrict__ T){
  int i = blockIdx.x, t = threadIdx.x;
  const float* row = D + (size_t)i * N;
  u64 key[16];
  #pragma unroll
  for (int q = 0; q < 4; q++){
    int l0 = t*4 + q*256;
    float4 f = *(const float4*)&row[l0];
    key[q*4+0] = ((u64)__float_as_uint(f.x) << 32) | (unsigned)(l0+0);
    key[q*4+1] = ((u64)__float_as_uint(f.y) << 32) | (unsigned)(l0+1);
    key[q*4+2] = ((u64)__float_as_uint(f.z) << 32) | (unsigned)(l0+2);
    key[q*4+3] = ((u64)__float_as_uint(f.w) << 32) | (unsigned)(l0+3);
  }
  for (int it = 0; it < 21; ++it){
    u64 m = key[0];
    #pragma unroll
    for (int q = 1; q < 16; q++) m = umin64(m, key[q]);
    #pragma unroll
    for (int off = 1; off < 64; off <<= 1) m = umin64(m, __shfl_xor(m, off));
    if (t == 0) T[i*21 + it] = (int)(m & 0xffffffffull);
    #pragma unroll
    for (int q = 0; q < 16; q++) if (key[q] == m) key[q] = ~0ull;
  }
}

// ---------------- reciprocal masks ----------------
__global__ __launch_bounds__(64) void recip_kernel(const int* __restrict__ T,
                                                   u64* __restrict__ Kb, u64* __restrict__ Khb){
  int i = blockIdx.x, t = threadIdx.x;
  __shared__ u64 kb[16], khb[16];
  if (t < 16){ kb[t] = 0; khb[t] = 0; }
  __syncthreads();
  if (t < 21){
    int j = T[i*21 + t];
    bool r21 = false, r11 = false;
    for (int p = 0; p < 21; p++){
      if (T[j*21 + p] == i){ r21 = true; if (p < 11) r11 = true; }
    }
    if (r21) atomicOr(&kb[j >> 6], 1ull << (j & 63));
    if (t < 11 && r11) atomicOr(&khb[j >> 6], 1ull << (j & 63));
  }
  __syncthreads();
  if (t < 16){ Kb[i*16 + t] = kb[t]; Khb[i*16 + t] = khb[t]; }
}

// ---------------- query expansion: 1 block per row, lane-parallel over neighbors ----------------
__global__ __launch_bounds__(64) void expand_kernel(const u64* __restrict__ Kb,
                                                    const u64* __restrict__ Khb,
                                                    u64* __restrict__ Eb){
  int i = blockIdx.x;
  int lane = threadIdx.x;
  __shared__ u64 er[16];
  __shared__ int js[32];
  __shared__ int njs;
  if (lane == 0) njs = 0;
  __syncthreads();
  if (lane < 16){
    u64 w = Kb[i*16 + lane];
    er[lane] = w;
    while (w){
      int bit = __ffsll((long long)w) - 1;
      w &= w - 1;
      int pos = atomicAdd(&njs, 1);
      js[pos] = lane*64 + bit;
    }
  }
  __syncthreads();
  if (lane < njs){
    int j = js[lane];
    int inter = 0, sz = 0;
    #pragma unroll
    for (int w = 0; w < 16; w++){
      u64 kh = Khb[(size_t)j*16 + w];
      u64 kw = Kb[(size_t)i*16 + w];
      inter += __popcll(kw & kh);
      sz += __popcll(kh);
    }
    if (3*inter > 2*sz){
      #pragma unroll
      for (int w = 0; w < 16; w++){
        u64 kh = Khb[(size_t)j*16 + w];
        if (kh) atomicOr(&er[w], kh);
      }
    }
  }
  __syncthreads();
  if (lane < 16) Eb[i*16 + lane] = er[lane];
}

// ---------------- V = rownorm(exp(-D0) * E) ----------------
__global__ __launch_bounds__(256) void v_kernel(const float* __restrict__ Dm,
                                                const u64* __restrict__ Eb,
                                                float* __restrict__ V){
  int i = blockIdx.x, t = threadIdx.x;
  float w[4];
  #pragma unroll
  for (int q = 0; q < 4; q++){
    int l = t + q*256;
    u64 word = Eb[i*16 + (l >> 6)];
    float e = expf(-Dm[(size_t)i * N + l]);
    w[q] = ((word >> (l & 63)) & 1ull) ? e : 0.f;
  }
  float s = w[0] + w[1] + w[2] + w[3];
  #pragma unroll
  for (int off = 32; off > 0; off >>= 1) s += __shfl_down(s, off);
  __shared__ float sm[4];
  __shared__ float stot;
  if ((t & 63) == 0) sm[t >> 6] = s;
  __syncthreads();
  if (t == 0){ float S = sm[0] + sm[1] + sm[2] + sm[3]; stot = (S == 0.f) ? 1.f : S; }
  __syncthreads();
  float denom = stot;
  #pragma unroll
  for (int q = 0; q < 4; q++){
    int l = t + q*256;
    V[(size_t)i * N + l] = w[q] / denom;
  }
}

// ---------------- Vbar[i] = mean of V over 6 nearest neighbors; fused VbS = OR of E rows ----------------
__global__ __launch_bounds__(256) void vbar_kernel(const float* __restrict__ V,
                                                   const int* __restrict__ T,
                                                   const u64* __restrict__ Eb,
                                                   float* __restrict__ Vb,
                                                   u64* __restrict__ VbS){
  int i = blockIdx.x, t = threadIdx.x;
  int t6[6];
  #pragma unroll
  for (int p = 0; p < 6; p++) t6[p] = T[i*21 + p];
  if (t < 16){
    u64 o = 0;
    #pragma unroll
    for (int p = 0; p < 6; p++) o |= Eb[(size_t)t6[p]*16 + t];
    VbS[i*16 + t] = o;
  }
  #pragma unroll
  for (int q = 0; q < 4; q++){
    int l = t + q*256;
    float s = 0.f;
    #pragma unroll
    for (int p = 0; p < 6; p++) s += V[(size_t)t6[p] * N + l];
    Vb[(size_t)i * N + l] = s / 6.0f;
  }
}

// ---------------- column-compressed Vb, atomic-free: block per column k ----------------
__global__ __launch_bounds__(256) void colbuild_kernel(const float* __restrict__ Vb,
                                                       const u64* __restrict__ VbS,
                                                       int* __restrict__ colCnt,
                                                       int* __restrict__ colJ,
                                                       float* __restrict__ colV){
  int k = blockIdx.x;
  int w = k >> 6, bshift = k & 63;
  int t = threadIdx.x;
  int lane = t & 63, wv = t >> 6;
  int cnt = 0;
  int js[4];
  #pragma unroll
  for (int e = 0; e < 4; e++){
    int j = t*4 + e;
    u64 word = VbS[(size_t)j*16 + w];
    if ((word >> bshift) & 1ull) js[cnt++] = j;
  }
  int incl = cnt;
  #pragma unroll
  for (int off = 1; off < 64; off <<= 1){
    int n = __shfl_up(incl, off);
    if (lane >= off) incl += n;
  }
  __shared__ int warpoff[4];
  if (lane == 63) warpoff[wv] = incl;
  __syncthreads();
  int wbase = 0;
  for (int v = 0; v < wv; v++) wbase += warpoff[v];
  int excl = wbase + incl - cnt;
  for (int e = 0; e < cnt; e++){
    int j = js[e];
    colJ[k*1024 + excl + e] = j;
    colV[k*1024 + excl + e] = Vb[(size_t)j*N + k];
  }
  if (t == 255) colCnt[k] = wbase + incl;
}

// ---------------- sparse jaccard: 4 LDS accumulators, barrier per 4 columns (r15-proven) ----------
__global__ __launch_bounds__(256) void jac_sparse_kernel(const float* __restrict__ Vb,
                                                         const u64* __restrict__ VbS,
                                                         const int* __restrict__ colCnt,
                                                         const int* __restrict__ colJ,
                                                         const float* __restrict__ colV,
                                                         float* __restrict__ Dm){
  int i = blockIdx.x, t = threadIdx.x;
  __shared__ float viRow[N];
  __shared__ float tmp[4][N];
  __shared__ u64 sbits[16];
  __shared__ int klist[N];
  __shared__ int warpoff[4];
  __shared__ int sS;
  #pragma unroll
  for (int q = 0; q < 4; q++){
    int l = t + q*256;
    viRow[l] = Vb[(size_t)i*N + l];
    tmp[0][l] = 0.f; tmp[1][l] = 0.f; tmp[2][l] = 0.f; tmp[3][l] = 0.f;
  }
  if (t < 16) sbits[t] = VbS[i*16 + t];
  __syncthreads();
  // build klist (ascending k) via scan compaction
  int lane = t & 63, wv = t >> 6;
  int cnt = 0; int ks[4];
  #pragma unroll
  for (int e = 0; e < 4; e++){
    int k = t*4 + e;
    if ((sbits[k >> 6] >> (k & 63)) & 1ull) ks[cnt++] = k;
  }
  int incl = cnt;
  #pragma unroll
  for (int off = 1; off < 64; off <<= 1){
    int n = __shfl_up(incl, off);
    if (lane >= off) incl += n;
  }
  if (lane == 63) warpoff[wv] = incl;
  __syncthreads();
  int wbase = 0;
  for (int v = 0; v < wv; v++) wbase += warpoff[v];
  int excl = wbase + incl - cnt;
  for (int e = 0; e < cnt; e++) klist[excl + e] = ks[e];
  if (t == 255) sS = wbase + incl;
  __syncthreads();
  int S = sS;
  for (int g0 = 0; g0 < S; g0 += 4){
    #pragma unroll
    for (int c = 0; c < 4; c++){
      int gi = g0 + c;
      if (gi < S){
        int k = klist[gi];
        float vik = viRow[k];
        int len = colCnt[k];
        const int*   cj = &colJ[k*1024];
        const float* cv = &colV[k*1024];
        for (int idx = t; idx < len; idx += 256){
          int j = cj[idx];
          tmp[c][j] += fminf(vik, cv[idx]);
        }
      }
    }
    __syncthreads();
  }
  #pragma unroll
  for (int q = 0; q < 4; q++){
    int l = t + q*256;
    float tm = (tmp[0][l] + tmp[1][l]) + (tmp[2][l] + tmp[3][l]);
    size_t off = (size_t)i*N + l;
    float d0 = Dm[off];
    Dm[off] = 0.7f * (1.0f - tm / (2.0f - tm)) + 0.3f * d0;
  }
}

// ---------------- dense jaccard fallback (small-workspace path) ----------------
__global__ __launch_bounds__(256) void jac_split_kernel(const float* __restrict__ Vb,
    float* __restrict__ p0, float* __restrict__ p1, int kc){
  __shared__ __align__(16) float As[32][64];
  __shared__ __align__(16) float Bs[32][64];
  int by, bx; tri_map(blockIdx.x, &by, &bx);
  int z = blockIdx.y;
  int t = threadIdx.x;
  int tx = t & 15, ty = t >> 4;
  int i0 = by * 64, j0 = bx * 64;
  int kbase = z * kc;
  int nslab = kc >> 5;
  int row0 = t >> 3, kq = t & 7;
  int sw = kq << 3;

  float4 fa0 = *(const float4*)&Vb[(size_t)(i0+row0)*N    + kbase + kq*4];
  float4 fa1 = *(const float4*)&Vb[(size_t)(i0+row0+32)*N + kbase + kq*4];
  float4 fb0 = *(const float4*)&Vb[(size_t)(j0+row0)*N    + kbase + kq*4];
  float4 fb1 = *(const float4*)&Vb[(size_t)(j0+row0+32)*N + kbase + kq*4];

  float acc[4][4] = {};
  for (int s = 0; s < nslab; s++){
    {
      float va0[4] = {fa0.x, fa0.y, fa0.z, fa0.w};
      float va1[4] = {fa1.x, fa1.y, fa1.z, fa1.w};
      float vb0[4] = {fb0.x, fb0.y, fb0.z, fb0.w};
      float vb1[4] = {fb1.x, fb1.y, fb1.z, fb1.w};
      #pragma unroll
      for (int e2 = 0; e2 < 4; e2++){
        As[kq*4+e2][row0 ^ sw]      = va0[e2];
        As[kq*4+e2][(row0+32) ^ sw] = va1[e2];
        Bs[kq*4+e2][row0 ^ sw]      = vb0[e2];
        Bs[kq*4+e2][(row0+32) ^ sw] = vb1[e2];
      }
    }
    __syncthreads();
    if (s + 1 < nslab){
      int k0 = kbase + (s+1)*32;
      fa0 = *(const float4*)&Vb[(size_t)(i0+row0)*N    + k0 + kq*4];
      fa1 = *(const float4*)&Vb[(size_t)(i0+row0+32)*N + k0 + kq*4];
      fb0 = *(const float4*)&Vb[(size_t)(j0+row0)*N    + k0 + kq*4];
      fb1 = *(const float4*)&Vb[(size_t)(j0+row0+32)*N + k0 + kq*4];
    }
    #pragma unroll
    for (int kk = 0; kk < 32; kk++){
      int swk = (kk >> 2) << 3;
      float4 a4 = *(const float4*)&As[kk][(ty*4) ^ swk];
      float4 b4 = *(const float4*)&Bs[kk][(tx*4) ^ swk];
      float av[4] = {a4.x, a4.y, a4.z, a4.w};
      float bv[4] = {b4.x, b4.y, b4.z, b4.w};
      #pragma unroll
      for (int r = 0; r < 4; r++){
        #pragma unroll
        for (int c = 0; c < 4; c++) acc[r][c] += fminf(av[r], bv[c]);
      }
    }
    __syncthreads();
  }
  float* P = (z == 0) ? p0 : p1 + (size_t)(z - 1) * N * N;
  #pragma unroll
  for (int r = 0; r < 4; r++){
    #pragma unroll
    for (int c = 0; c < 4; c++){
      int i = i0 + ty*4 + r, j = j0 + tx*4 + c;
      P[(size_t)i * N + j] = acc[r][c];
    }
  }
}

__global__ __launch_bounds__(256) void jac_combine_kernel(
    const float* __restrict__ p0, const float* __restrict__ p1,
    int nsplit, float* __restrict__ Dm){
  __shared__ float Ts[32][68];
  int by, bx; tri_map(blockIdx.x, &by, &bx);
  int h = blockIdx.y;
  int t = threadIdx.x;
  int tc = t & 15, tr = t >> 4;
  int i0 = by * 64 + h * 32, j0 = bx * 64;
  #pragma unroll
  for (int rr = 0; rr < 2; rr++){
    int r = tr*2 + rr;
    int i = i0 + r;
    size_t off = (size_t)i * N + j0 + tc*4;
    float4 s = *(const float4*)&p0[off];
    for (int z = 1; z < nsplit; z++){
      float4 q = *(const float4*)&p1[(size_t)(z-1)*N*N + off];
      s.x += q.x; s.y += q.y; s.z += q.z; s.w += q.w;
    }
    float4 d0 = *(const float4*)&Dm[off];
    float4 o;
    o.x = 0.7f * (1.0f - s.x / (2.0f - s.x)) + 0.3f * d0.x;
    o.y = 0.7f * (1.0f - s.y / (2.0f - s.y)) + 0.3f * d0.y;
    o.z = 0.7f * (1.0f - s.z / (2.0f - s.z)) + 0.3f * d0.z;
    o.w = 0.7f * (1.0f - s.w / (2.0f - s.w)) + 0.3f * d0.w;
    *(float4*)&Dm[off] = o;
    Ts[r][tc*4+0] = o.x; Ts[r][tc*4+1] = o.y;
    Ts[r][tc*4+2] = o.z; Ts[r][tc*4+3] = o.w;
  }
  if (by == bx) return;
  __syncthreads();
  int tc2 = t & 7, jr0 = t >> 3;
  #pragma unroll
  for (int e = 0; e < 2; e++){
    int c = jr0 + e*32;
    float4 o;
    o.x = Ts[tc2*4+0][c];
    o.y = Ts[tc2*4+1][c];
    o.z = Ts[tc2*4+2][c];
    o.w = Ts[tc2*4+3][c];
    *(float4*)&Dm[(size_t)(j0 + c) * N + i0 + tc2*4] = o;
  }
}

// ---------------- dist_ap / dist_an ----------------
__global__ __launch_bounds__(256) void apan_kernel(const float* __restrict__ Dm,
                                                   const int* __restrict__ tg,
                                                   float* __restrict__ ap, float* __restrict__ an){
  int i = blockIdx.x, t = threadIdx.x;
  int ti = tg[i];
  float mx = -3.402823466e38f, mn = 3.402823466e38f;
  #pragma unroll
  for (int q = 0; q < 4; q++){
    int l = t + q*256;
    float v = Dm[(size_t)i * N + l];
    if (tg[l] == ti) mx = fmaxf(mx, v); else mn = fminf(mn, v);
  }
  #pragma unroll
  for (int off = 32; off > 0; off >>= 1){
    mx = fmaxf(mx, __shfl_down(mx, off));
    mn = fminf(mn, __shfl_down(mn, off));
  }
  __shared__ float smx[4], smn[4];
  if ((t & 63) == 0){ smx[t >> 6] = mx; smn[t >> 6] = mn; }
  __syncthreads();
  if (t == 0){
    ap[i] = fmaxf(fmaxf(smx[0], smx[1]), fmaxf(smx[2], smx[3]));
    an[i] = fminf(fminf(smn[0], smn[1]), fminf(smn[2], smn[3]));
  }
}

// ---------------- loss ----------------
__global__ __launch_bounds__(256) void loss_kernel(const float* __restrict__ ap,
                                                   const float* __restrict__ an,
                                                   float* __restrict__ out){
  int t = threadIdx.x;
  float s = 0.f;
  #pragma unroll
  for (int q = 0; q < 4; q++){
    int l = t + q*256;
    s += fmaxf(ap[l] - an[l] + 0.03f, 0.f);
  }
  #pragma unroll
  for (int off = 32; off > 0; off >>= 1) s += __shfl_down(s, off);
  __shared__ float sm[4];
  if ((t & 63) == 0) sm[t >> 6] = s;
  __syncthreads();
  if (t == 0) out[0] = (sm[0] + sm[1] + sm[2] + sm[3]) / 1024.0f;
}

// ---------------- launch ----------------
static const size_t XX_OFF  = 0;          // 1024 f32
static const size_t T_OFF   = 4096;       // 1024*21 i32
static const size_t KB_OFF  = 90112;      // 1024*16 u64
static const size_t KHB_OFF = 221184;
static const size_t EB_OFF  = 352256;
static const size_t V_OFF   = 483328;     // 1024*1024 f32 (doubles as partial 0)
static const size_t VB_OFF  = 4677632;    // 1024*1024 f32
static const size_t P1_OFF  = 8871936;    // gemm partials 1..nsplit-1; later reused for sparse structs
static const size_t NN4     = 4194304;    // N*N*4 bytes
// sparse jaccard structures (temporal reuse of P1 region, after gemm_combine):
static const size_t CJ_REL   = 0;                  // colJ: 1024*1024 i32 = 4MB
static const size_t CV_REL   = 4194304;            // colV: 1024*1024 f32 = 4MB
static const size_t CC_REL   = 8388608;            // colCnt: 1024 i32 = 4KB
static const size_t VBS_REL  = 8392704;            // VbS: 1024*16 u64 = 128KB
static const size_t SPARSE_NEED = 8523776;         // CJ+CV+CC+VBS

extern "C" void kernel_launch(void* const* d_in, const int* in_sizes, int n_in,
                              void* d_out, int out_size, void* d_ws, size_t ws_size,
                              hipStream_t stream){
  const float* x  = (const float*)d_in[0];
  const int*   tg = (const int*)d_in[1];
  float* out = (float*)d_out;
  char* ws = (char*)d_ws;
  if (ws_size < P1_OFF) return;

  float* xx  = (float*)(ws + XX_OFF);
  int*   T   = (int*)(ws + T_OFF);
  u64*   Kb  = (u64*)(ws + KB_OFF);
  u64*   Khb = (u64*)(ws + KHB_OFF);
  u64*   Eb  = (u64*)(ws + EB_OFF);
  float* V   = (float*)(ws + V_OFF);
  float* Vb  = (float*)(ws + VB_OFF);

  float* dist = out + 1;
  float* ap   = out + 1 + (size_t)N*N;
  float* an   = ap + N;

  size_t avail = ws_size - P1_OFF;
  int nsplit = (avail >= 7*NN4) ? 8 : (avail >= 3*NN4) ? 4 : (avail >= 1*NN4) ? 2 : 1;
  float* P0 = V;                       // V buffer is free until v_kernel
  float* P1 = (float*)(ws + P1_OFF);   // gemm partials z=1..nsplit-1

  bool use_sparse = (avail >= SPARSE_NEED);
  int*   colJ   = (int*)(ws + P1_OFF + CJ_REL);
  float* colV   = (float*)(ws + P1_OFF + CV_REL);
  int*   colCnt = (int*)(ws + P1_OFF + CC_REL);
  u64*   VbS    = (u64*)(ws + P1_OFF + VBS_REL);

  rownorm_kernel     <<<N, 256, 0, stream>>>(x, xx);
  gemm_split_kernel  <<<dim3(136, nsplit), 256, 0, stream>>>(x, P0, P1, DIM/nsplit);
  gemm_combine_kernel<<<dim3(136, 2), 256, 0, stream>>>(P0, P1, nsplit, xx, dist);
  topk_kernel        <<<N, 64, 0, stream>>>(dist, T);
  recip_kernel       <<<N, 64, 0, stream>>>(T, Kb, Khb);
  expand_kernel      <<<N, 64, 0, stream>>>(Kb, Khb, Eb);
  v_kernel           <<<N, 256, 0, stream>>>(dist, Eb, V);
  if (use_sparse){
    vbar_kernel      <<<N, 256, 0, stream>>>(V, T, Eb, Vb, VbS);
    colbuild_kernel  <<<N, 256, 0, stream>>>(Vb, VbS, colCnt, colJ, colV);
    jac_sparse_kernel<<<N, 256, 0, stream>>>(Vb, VbS, colCnt, colJ, colV, dist);
  } else {
    vbar_kernel      <<<N, 256, 0, stream>>>(V, T, Eb, Vb, VbS);
    jac_split_kernel <<<dim3(136, nsplit), 256, 0, stream>>>(Vb, P0, P1, N/nsplit);
    jac_combine_kernel<<<dim3(136, 2), 256, 0, stream>>>(P0, P1, nsplit, dist);
  }
  apan_kernel        <<<N, 256, 0, stream>>>(dist, tg, ap, an);
  loss_kernel        <<<1, 256, 0, stream>>>(ap, an, out);
}